// Round 10
// baseline (378.572 us; speedup 1.0000x reference)
//
#include <hip/hip_runtime.h>

#define SEQ  2048
#define EMB  1024
#define NBAT 8
#define NROW (NBAT*SEQ)   // 16384

using u16 = unsigned short;
typedef float  f32x4  __attribute__((ext_vector_type(4)));
typedef __bf16 bf16x8 __attribute__((ext_vector_type(8)));
typedef u16    u16x8  __attribute__((ext_vector_type(8)));
typedef u16    u16x4  __attribute__((ext_vector_type(4)));

__device__ __forceinline__ u16 f2bf(float x) {
  unsigned u = __builtin_bit_cast(unsigned, x);
  return (u16)((u + 0x7fffu + ((u >> 16) & 1u)) >> 16);  // RNE, finite inputs
}
__device__ __forceinline__ float bf2f(u16 h) {
  return __builtin_bit_cast(float, ((unsigned)h) << 16);
}

__device__ __forceinline__ f32x4 mfma16(u16x8 a, u16x8 b, f32x4 c) {
  return __builtin_amdgcn_mfma_f32_16x16x32_bf16(
      __builtin_bit_cast(bf16x8, a), __builtin_bit_cast(bf16x8, b), c, 0, 0, 0);
}

__device__ __forceinline__ void async_cp16(const u16* g, u16* l) {
  __builtin_amdgcn_global_load_lds(
      (const __attribute__((address_space(1))) void*)(g),
      (__attribute__((address_space(3))) void*)(l), 16, 0, 0);
}

// ---- 256x32 tile staging with the R6-proven XOR swizzle (both sides).
// 2 global_load_lds per wave; 8 waves cover 256 rows.
__device__ __forceinline__ void stage_half(const u16* __restrict__ g, int ld,
                                           u16* __restrict__ lds, int wid, int lane)
{
  const int lr = lane >> 2;
  const int bb = (lr & 1) ^ ((lr >> 2) & 1);
  const int row16 = (lr & ~1) | bb;
  const int ck = (lane & 3) ^ ((lr & 2) | bb);
#pragma unroll
  for (int l = 0; l < 2; ++l) {
    const int r0 = wid * 32 + l * 16;
    async_cp16(g + (size_t)(r0 + row16) * ld + ck * 8, lds + r0 * 32);
  }
}

// 8 A-frag reads (the wave's 128 rows) from a [256][32] buffer.
__device__ __forceinline__ void ph_reads_A8(const u16* __restrict__ sAh,
                                            int wr, int r, int kg, int xr, u16x8 a[8])
{
#pragma unroll
  for (int i = 0; i < 8; ++i) {
    const int row = wr * 128 + i * 16 + r;
    a[i] = *(const u16x8*)&sAh[(row * 32 + kg * 8) ^ xr];
  }
}
__device__ __forceinline__ void ph_reads_B(const u16* __restrict__ sBh,
                                           int wc, int r, int kg, int xr, u16x8 b[4])
{
#pragma unroll
  for (int j = 0; j < 4; ++j) {
    const int row = wc * 64 + j * 16 + r;
    b[j] = *(const u16x8*)&sBh[(row * 32 + kg * 8) ^ xr];
  }
}

__device__ __forceinline__ void mfma_block8(const u16x8 a[8], const u16x8 b[4],
                                            f32x4 (*accp)[4])
{
#pragma unroll
  for (int i = 0; i < 8; ++i)
#pragma unroll
    for (int j = 0; j < 4; ++j)
      accp[i][j] = mfma16(a[i], b[j], accp[i][j]);
}

// One BK=32 step at 256^2: 12 ds_read_b128 + 32 MFMA (setprio'd cluster).
__device__ __forceinline__ void kstep256(const u16* __restrict__ sA,
                                         const u16* __restrict__ sB,
                                         int wr, int wc, int lane, f32x4 (*acc)[4])
{
  const int r = lane & 15, kg = lane >> 4;
  const int xr = (r & 7) << 3;
  u16x8 a[8], b[4];
  ph_reads_B(sB, wc, r, kg, xr, b);
  ph_reads_A8(sA, wr, r, kg, xr, a);
  __builtin_amdgcn_s_setprio(1);
  mfma_block8(a, b, acc);
  __builtin_amdgcn_s_setprio(0);
}

// R5's proven 3-buffer counted-vmcnt pipeline at 256^2/BK=32 (96 KB LDS).
// Per iter: vmcnt(4) [pre-barrier: publishes MY t-batch to all waves] ->
// barrier -> STAGE(t+2) -> kstep(t). 4 stage-instrs/step, so the R5
// accounting transfers verbatim: at iter top outstanding = 8 (t,t+1... ->
// wait to 4 leaves t+1's 4 in flight). Never drains to 0 until last tile.
#define GEMM_PIPE3(Aptr, ldA, Bptr, ldB, NTv)                        \
  stage_half((Aptr), (ldA), sA0, wid, lane);                         \
  stage_half((Bptr), (ldB), sB0, wid, lane);                         \
  stage_half((Aptr) + 32, (ldA), sA1, wid, lane);                    \
  stage_half((Bptr) + 32, (ldB), sB1, wid, lane);                    \
  {                                                                  \
    u16 *pa0 = sA0, *pa1 = sA1, *pa2 = sA2;                          \
    u16 *pb0 = sB0, *pb1 = sB1, *pb2 = sB2;                          \
    for (int tt = 0; tt < (NTv) - 1; ++tt) {                         \
      asm volatile("s_waitcnt vmcnt(4)" ::: "memory");               \
      __builtin_amdgcn_s_barrier();                                  \
      __builtin_amdgcn_sched_barrier(0);                             \
      if (tt + 2 < (NTv)) {                                          \
        stage_half((Aptr) + (tt + 2) * 32, (ldA), pa2, wid, lane);   \
        stage_half((Bptr) + (tt + 2) * 32, (ldB), pb2, wid, lane);   \
      }                                                              \
      kstep256(pa0, pb0, wr, wc, lane, acc);                         \
      u16* tmp = pa0; pa0 = pa1; pa1 = pa2; pa2 = tmp;               \
      tmp = pb0; pb0 = pb1; pb1 = pb2; pb2 = tmp;                    \
    }                                                                \
    asm volatile("s_waitcnt vmcnt(0)" ::: "memory");                 \
    __builtin_amdgcn_s_barrier();                                    \
    __builtin_amdgcn_sched_barrier(0);                               \
    kstep256(pa0, pb0, wr, wc, lane, acc);                           \
  }

#define DECL_LDS_PIPE3()                                             \
  __shared__ alignas(16) u16 sA0[256 * 32], sA1[256 * 32], sA2[256 * 32]; \
  __shared__ alignas(16) u16 sB0[256 * 32], sB1[256 * 32], sB2[256 * 32]

#define DECL_ACC()                                                   \
  f32x4 acc[8][4];                                                   \
  _Pragma("unroll")                                                  \
  for (int i = 0; i < 8; ++i)                                        \
    _Pragma("unroll")                                                \
    for (int j = 0; j < 4; ++j)                                      \
      _Pragma("unroll")                                              \
      for (int q = 0; q < 4; ++q) acc[i][j][q] = 0.0f

__device__ __forceinline__ int xcd_swz(int bid, int nwg) {
  return (bid & 7) * (nwg >> 3) + (bid >> 3);
}

// ---- 1) One-shot bf16 conversion of X and Wq/Wk/Wv.
__global__ __launch_bounds__(256) void prep_kernel(
    const float* __restrict__ X,
    const float* __restrict__ Wq, const float* __restrict__ Wk, const float* __restrict__ Wv,
    u16* __restrict__ Xb, u16* __restrict__ Wb)
{
  const size_t i = ((size_t)blockIdx.x * 256 + threadIdx.x) * 4;
  const size_t nx = (size_t)NROW * EMB;
  f32x4 v;
  u16* dst;
  if (i < nx) {
    v = *(const f32x4*)(X + i);
    dst = Xb + i;
  } else {
    const size_t j = i - nx;
    const int m = (int)(j / ((size_t)EMB * EMB));
    const size_t o = j - (size_t)m * EMB * EMB;
    const float* W = (m == 0) ? Wq : (m == 1) ? Wk : Wv;
    v = *(const f32x4*)(W + o);
    dst = Wb + j;
  }
  u16x4 h;
#pragma unroll
  for (int j = 0; j < 4; ++j) h[j] = f2bf(v[j]);
  *(u16x4*)dst = h;
}

// ---- 2) Fused QKV projection, 256^2 / BK=32 / 3-buf pipeline
__global__ __launch_bounds__(512, 2) void proj_kernel(
    const u16* __restrict__ Xb, const u16* __restrict__ Wb,
    const float* __restrict__ bq, const float* __restrict__ bk, const float* __restrict__ bv,
    u16* __restrict__ Qb, u16* __restrict__ Kb, u16* __restrict__ VT)
{
  DECL_LDS_PIPE3();
  const int nwg = 4 * 64 * 3;                           // 768
  int wg = xcd_swz(blockIdx.x, nwg);
  const int n0 = (wg & 3) * 256;        wg >>= 2;
  const int m0 = (wg & 63) * 256;       wg >>= 6;
  const int mat = wg;

  const int t = threadIdx.x, lane = t & 63, wid = t >> 6;
  const int wr = wid >> 2, wc = wid & 3;

  const u16* A = Xb + (size_t)m0 * EMB;
  const u16* B = Wb + (size_t)mat * EMB * EMB + (size_t)n0 * EMB;

  DECL_ACC();
  GEMM_PIPE3(A, EMB, B, EMB, EMB / 32);

  const float* bias = (mat == 0) ? bq : (mat == 1) ? bk : bv;
  const int r = lane & 15, kg = lane >> 4;
#pragma unroll
  for (int i = 0; i < 8; ++i) {
#pragma unroll
    for (int j = 0; j < 4; ++j) {
      const int c = n0 + wc * 64 + j * 16 + r;
      const float bb = bias[c];
      if (mat == 2) {
        const int bi = m0 >> 11;
        const int sbase = (m0 & (SEQ - 1)) + wr * 128 + i * 16 + kg * 4;
        u16x4 hv;
#pragma unroll
        for (int rg = 0; rg < 4; ++rg) hv[rg] = f2bf(acc[i][j][rg] + bb);
        *(u16x4*)&VT[((size_t)bi * EMB + c) * SEQ + sbase] = hv;   // V^T, rg-packed
      } else {
        u16* D = (mat == 0) ? Qb : Kb;
#pragma unroll
        for (int rg = 0; rg < 4; ++rg) {
          const int row = m0 + wr * 128 + i * 16 + kg * 4 + rg;
          D[(size_t)row * EMB + c] = f2bf(acc[i][j][rg] + bb);
        }
      }
    }
  }
}

// ---- 3) scores: e = bf16(exp(gq*gk*QK/32)) -> raw (unnormalized weights).
// No max subtraction: |s| <= ~2 at this problem's scale — overflow-safe,
// mathematically identical to softmax.
__global__ __launch_bounds__(512, 2) void scores_kernel(
    const u16* __restrict__ Qb, const u16* __restrict__ Kb,
    const float* __restrict__ gates, u16* __restrict__ raw)
{
  DECL_LDS_PIPE3();
  const int nwg = 8 * 8 * NBAT;                         // 512
  int wg = xcd_swz(blockIdx.x, nwg);
  const int n0 = (wg & 7) * 256;        wg >>= 3;
  const int q0 = (wg & 7) * 256;        wg >>= 3;
  const int b  = wg;

  const int t = threadIdx.x, lane = t & 63, wid = t >> 6;
  const int wr = wid >> 2, wc = wid & 3;

  const u16* A = Qb + ((size_t)b * SEQ + q0) * EMB;
  const u16* B = Kb + ((size_t)b * SEQ + n0) * EMB;

  DECL_ACC();
  GEMM_PIPE3(A, EMB, B, EMB, EMB / 32);

  const float* gb = gates + (size_t)b * SEQ;
  u16* rawB = raw + ((size_t)b * SEQ + q0) * SEQ;
  const int r = lane & 15, kg = lane >> 4;

  float gkj[4];
#pragma unroll
  for (int j = 0; j < 4; ++j) gkj[j] = gb[n0 + wc * 64 + j * 16 + r] * 0.03125f;

#pragma unroll
  for (int i = 0; i < 8; ++i) {
#pragma unroll
    for (int rg = 0; rg < 4; ++rg) {
      const int qr = wr * 128 + i * 16 + kg * 4 + rg;
      const float gq = gb[q0 + qr];
#pragma unroll
      for (int j = 0; j < 4; ++j) {
        const int col = n0 + wc * 64 + j * 16 + r;
        rawB[(size_t)qr * SEQ + col] = f2bf(expf(acc[i][j][rg] * gq * gkj[j]));
      }
    }
  }
}

// ---- 4) rownorm: L = sum(e) per row; attn = e/L (f32 output); invl for pv
__global__ __launch_bounds__(256) void rownorm_kernel(
    const u16* __restrict__ raw, float* __restrict__ attn, float* __restrict__ invl)
{
  const int row = blockIdx.x;
  const int t = threadIdx.x, lane = t & 63, wid = t >> 6;
  const u16* rp = raw + (size_t)row * SEQ + t * 8;
  u16x8 h = *(const u16x8*)rp;
  float e[8];
  float s = 0.f;
#pragma unroll
  for (int j = 0; j < 8; ++j) { e[j] = bf2f(h[j]); s += e[j]; }
#pragma unroll
  for (int off = 32; off >= 1; off >>= 1) s += __shfl_xor(s, off);
  __shared__ float red[4];
  if (lane == 0) red[wid] = s;
  __syncthreads();
  s = (red[0] + red[1]) + (red[2] + red[3]);
  const float iv = 1.0f / s;
  float* ap = attn + (size_t)row * SEQ + t * 8;
  f32x4 w0, w1;
#pragma unroll
  for (int j = 0; j < 4; ++j) { w0[j] = e[j] * iv; w1[j] = e[j + 4] * iv; }
  *(f32x4*)ap       = w0;
  *(f32x4*)(ap + 4) = w1;
  if (t == 0) invl[row] = iv;
}

// ---- 5) pv: out = (E * V) * invL, 256^2 / BK=32 / 3-buf pipeline
__global__ __launch_bounds__(512, 2) void pv_kernel(
    const u16* __restrict__ Eb, const u16* __restrict__ VT,
    const float* __restrict__ invl, float* __restrict__ out)
{
  DECL_LDS_PIPE3();
  const int nwg = 4 * 8 * NBAT;                         // 256
  int wg = xcd_swz(blockIdx.x, nwg);
  const int d0 = (wg & 3) * 256;        wg >>= 2;
  const int q0 = (wg & 7) * 256;        wg >>= 3;
  const int b  = wg;

  const int t = threadIdx.x, lane = t & 63, wid = t >> 6;
  const int wr = wid >> 2, wc = wid & 3;

  const u16* A = Eb + ((size_t)b * SEQ + q0) * SEQ;     // unnormalized weights bf16
  const u16* B = VT + ((size_t)b * EMB + d0) * SEQ;     // V^T [d][k]

  DECL_ACC();
  GEMM_PIPE3(A, SEQ, B, SEQ, SEQ / 32);

  const int r = lane & 15, kg = lane >> 4;
#pragma unroll
  for (int i = 0; i < 8; ++i) {
#pragma unroll
    for (int rg = 0; rg < 4; ++rg) {
      const int rowl = q0 + wr * 128 + i * 16 + kg * 4 + rg;
      const float iv = invl[(size_t)b * SEQ + rowl];
#pragma unroll
      for (int j = 0; j < 4; ++j) {
        const int col = d0 + wc * 64 + j * 16 + r;
        out[((size_t)b * SEQ + rowl) * EMB + col] = acc[i][j][rg] * iv;
      }
    }
  }
}

extern "C" void kernel_launch(void* const* d_in, const int* in_sizes, int n_in,
                              void* d_out, int out_size, void* d_ws, size_t ws_size,
                              hipStream_t stream) {
  const float* X  = (const float*)d_in[0];
  const float* g  = (const float*)d_in[1];
  const float* Wq = (const float*)d_in[2];
  const float* bq = (const float*)d_in[3];
  const float* Wk = (const float*)d_in[4];
  const float* bk = (const float*)d_in[5];
  const float* Wv = (const float*)d_in[6];
  const float* bv = (const float*)d_in[7];

  float* out0 = (float*)d_out;
  float* attn = out0 + (size_t)NROW * EMB;

  // ws: [region0 67MB: raw bf16 e-values; overlaid by Xb(33.5)+Wb(6.3) during
  //  prep/proj (dead before scores writes)] [VT 33.5MB] [invl 64KB] = ~101 MB
  const size_t rawN = (size_t)NBAT * SEQ * SEQ;          // 33,554,432 u16
  const size_t need = rawN * 2 + (size_t)NBAT * EMB * SEQ * 2 + (size_t)NROW * 4;
  if (ws_size < need) return;
  u16* region0 = (u16*)d_ws;
  u16* Xb  = region0;
  u16* Wb  = region0 + (size_t)NROW * EMB;
  u16* raw = region0;
  u16* VT  = region0 + rawN;
  float* invl = (float*)(VT + (size_t)NBAT * EMB * SEQ);
  // Qb/Kb live in out0 (dead until pv overwrites it)
  u16* Qb = (u16*)out0;
  u16* Kb = Qb + (size_t)NROW * EMB;

  const int prep_blocks = (int)(((size_t)NROW * EMB + (size_t)3 * EMB * EMB) / 1024);
  prep_kernel   <<<dim3(prep_blocks), 256, 0, stream>>>(X, Wq, Wk, Wv, Xb, Wb);
  proj_kernel   <<<dim3(768), 512, 0, stream>>>(Xb, Wb, bq, bk, bv, Qb, Kb, VT);
  scores_kernel <<<dim3(512), 512, 0, stream>>>(Qb, Kb, g, raw);
  rownorm_kernel<<<dim3(NROW), 256, 0, stream>>>(raw, attn, invl);
  pv_kernel     <<<dim3(256), 512, 0, stream>>>(raw, VT, invl, out0);
}

// Round 11
// 354.232 us; speedup vs baseline: 1.0687x; 1.0687x over previous
//
#include <hip/hip_runtime.h>

#define SEQ  2048
#define EMB  1024
#define NBAT 8
#define NROW (NBAT*SEQ)   // 16384

using u16 = unsigned short;
typedef float  f32x4  __attribute__((ext_vector_type(4)));
typedef __bf16 bf16x8 __attribute__((ext_vector_type(8)));
typedef u16    u16x8  __attribute__((ext_vector_type(8)));
typedef u16    u16x4  __attribute__((ext_vector_type(4)));

__device__ __forceinline__ u16 f2bf(float x) {
  unsigned u = __builtin_bit_cast(unsigned, x);
  return (u16)((u + 0x7fffu + ((u >> 16) & 1u)) >> 16);  // RNE, finite inputs
}
__device__ __forceinline__ float bf2f(u16 h) {
  return __builtin_bit_cast(float, ((unsigned)h) << 16);
}

__device__ __forceinline__ f32x4 mfma16(u16x8 a, u16x8 b, f32x4 c) {
  return __builtin_amdgcn_mfma_f32_16x16x32_bf16(
      __builtin_bit_cast(bf16x8, a), __builtin_bit_cast(bf16x8, b), c, 0, 0, 0);
}

__device__ __forceinline__ void async_cp16(const u16* g, u16* l) {
  __builtin_amdgcn_global_load_lds(
      (const __attribute__((address_space(1))) void*)(g),
      (__attribute__((address_space(3))) void*)(l), 16, 0, 0);
}

__device__ __forceinline__ int xcd_swz(int bid, int nwg) {
  return (bid & 7) * (nwg >> 3) + (bid >> 3);
}

// ======================= 128^2 family (proj — R5-proven) =======================
// Linear 128x32 staging (4 waves, 256 threads).
__device__ __forceinline__ void gload_tile128(const u16* __restrict__ g, int ld,
                                              u16* __restrict__ lds, int wid, int lane)
{
#pragma unroll
  for (int l = 0; l < 2; ++l) {
    const int r0 = wid * 32 + l * 16;
    const u16* src = g + (size_t)(r0 + (lane >> 2)) * ld + (lane & 3) * 8;
    async_cp16(src, lds + r0 * 32);
  }
}

// 8 ds_read_b128 + 16 MFMA (R5 exact: no swizzle, no setprio).
__device__ __forceinline__ void kstep128(const u16* __restrict__ sA,
                                         const u16* __restrict__ sB,
                                         int wr, int wc, int lane, f32x4 acc[4][4])
{
  const int r = lane & 15, kg = lane >> 4;
  u16x8 a[4], b[4];
#pragma unroll
  for (int i = 0; i < 4; ++i) {
    a[i] = *(const u16x8*)&sA[(wr * 64 + i * 16 + r) * 32 + kg * 8];
    b[i] = *(const u16x8*)&sB[(wc * 64 + i * 16 + r) * 32 + kg * 8];
  }
#pragma unroll
  for (int i = 0; i < 4; ++i)
#pragma unroll
    for (int j = 0; j < 4; ++j)
      acc[i][j] = mfma16(a[i], b[j], acc[i][j]);
}

// R5's 3-buffer counted-vmcnt pipeline. vmcnt pre-barrier (publishes to all).
#define GEMM_PIPE3_128(Aptr, ldA, Bptr, ldB, NTv)                    \
  gload_tile128((Aptr), (ldA), sA0, wid, lane);                      \
  gload_tile128((Bptr), (ldB), sB0, wid, lane);                      \
  gload_tile128((Aptr) + 32, (ldA), sA1, wid, lane);                 \
  gload_tile128((Bptr) + 32, (ldB), sB1, wid, lane);                 \
  {                                                                  \
    u16 *pa0 = sA0, *pa1 = sA1, *pa2 = sA2;                          \
    u16 *pb0 = sB0, *pb1 = sB1, *pb2 = sB2;                          \
    for (int tt = 0; tt < (NTv) - 1; ++tt) {                         \
      asm volatile("s_waitcnt vmcnt(4)" ::: "memory");               \
      __builtin_amdgcn_s_barrier();                                  \
      __builtin_amdgcn_sched_barrier(0);                             \
      if (tt + 2 < (NTv)) {                                          \
        gload_tile128((Aptr) + (tt + 2) * 32, (ldA), pa2, wid, lane);\
        gload_tile128((Bptr) + (tt + 2) * 32, (ldB), pb2, wid, lane);\
      }                                                              \
      kstep128(pa0, pb0, wr, wc, lane, acc);                         \
      u16* tmp = pa0; pa0 = pa1; pa1 = pa2; pa2 = tmp;               \
      tmp = pb0; pb0 = pb1; pb1 = pb2; pb2 = tmp;                    \
    }                                                                \
    asm volatile("s_waitcnt vmcnt(0)" ::: "memory");                 \
    __builtin_amdgcn_s_barrier();                                    \
    __builtin_amdgcn_sched_barrier(0);                               \
    kstep128(pa0, pb0, wr, wc, lane, acc);                           \
  }

// ======================= 256^2 family (scores/pv — R9-proven) ==================
__device__ __forceinline__ void stage_half(const u16* __restrict__ g, int ld,
                                           u16* __restrict__ lds, int wid, int lane)
{
  const int lr = lane >> 2;
  const int bb = (lr & 1) ^ ((lr >> 2) & 1);
  const int row16 = (lr & ~1) | bb;
  const int ck = (lane & 3) ^ ((lr & 2) | bb);
#pragma unroll
  for (int l = 0; l < 2; ++l) {
    const int r0 = wid * 32 + l * 16;
    async_cp16(g + (size_t)(r0 + row16) * ld + ck * 8, lds + r0 * 32);
  }
}

__device__ __forceinline__ void ph_reads_A8(const u16* __restrict__ sAh,
                                            int wr, int r, int kg, int xr, u16x8 a[8])
{
#pragma unroll
  for (int i = 0; i < 8; ++i) {
    const int row = wr * 128 + i * 16 + r;
    a[i] = *(const u16x8*)&sAh[(row * 32 + kg * 8) ^ xr];
  }
}
__device__ __forceinline__ void ph_reads_B(const u16* __restrict__ sBh,
                                           int wc, int r, int kg, int xr, u16x8 b[4])
{
#pragma unroll
  for (int j = 0; j < 4; ++j) {
    const int row = wc * 64 + j * 16 + r;
    b[j] = *(const u16x8*)&sBh[(row * 32 + kg * 8) ^ xr];
  }
}

__device__ __forceinline__ void mfma_block8(const u16x8 a[8], const u16x8 b[4],
                                            f32x4 (*accp)[4])
{
#pragma unroll
  for (int i = 0; i < 8; ++i)
#pragma unroll
    for (int j = 0; j < 4; ++j)
      accp[i][j] = mfma16(a[i], b[j], accp[i][j]);
}

#define DECL_LDS_2PH()                                                       \
  __shared__ alignas(16) u16 sAls[2][2][256 * 32];                           \
  __shared__ alignas(16) u16 sBls[2][2][256 * 32]

#define PH2(READS, STAGE, WAIT)                                              \
  READS                                                                      \
  STAGE                                                                      \
  WAIT                                                                       \
  __builtin_amdgcn_s_barrier();                                              \
  asm volatile("s_waitcnt lgkmcnt(0)" ::: "memory");                         \
  __builtin_amdgcn_sched_barrier(0);                                         \
  __builtin_amdgcn_s_setprio(1);                                             \
  mfma_block8(a_, b_, acc);                                                  \
  __builtin_amdgcn_s_setprio(0);                                             \
  __builtin_amdgcn_s_barrier();

#define GEMM_2PH(Aptr, ldA, Bptr, ldB, NTv)                                  \
  {                                                                          \
    const int r_ = lane & 15, kg_ = lane >> 4;                               \
    const int xr_ = (r_ & 7) << 3;                                           \
    stage_half((Aptr),      (ldA), &sAls[0][0][0], wid, lane);               \
    stage_half((Aptr) + 32, (ldA), &sAls[0][1][0], wid, lane);               \
    stage_half((Bptr),      (ldB), &sBls[0][0][0], wid, lane);               \
    stage_half((Bptr) + 32, (ldB), &sBls[0][1][0], wid, lane);               \
    asm volatile("s_waitcnt vmcnt(2)" ::: "memory");                         \
    __builtin_amdgcn_sched_barrier(0);                                       \
    __builtin_amdgcn_s_barrier();                                            \
    u16x8 a_[8], b_[4];                                                      \
    for (int tt = 0; tt < (NTv); ++tt) {                                     \
      const int s_ = tt & 1, s2_ = s_ ^ 1;                                   \
      const u16* A0_ = &sAls[s_][0][0]; const u16* A1_ = &sAls[s_][1][0];    \
      const u16* B0_ = &sBls[s_][0][0]; const u16* B1_ = &sBls[s_][1][0];    \
      const bool pf_ = (tt + 1 < (NTv));                                     \
      PH2({ ph_reads_A8(A0_, wr, r_, kg_, xr_, a_);                          \
            ph_reads_B(B0_, wc, r_, kg_, xr_, b_); },                        \
          { if (pf_) {                                                       \
              stage_half((Aptr) + (tt + 1) * 64,      (ldA),                 \
                         &sAls[s2_][0][0], wid, lane);                       \
              stage_half((Aptr) + (tt + 1) * 64 + 32, (ldA),                 \
                         &sAls[s2_][1][0], wid, lane);                       \
              stage_half((Bptr) + (tt + 1) * 64,      (ldB),                 \
                         &sBls[s2_][0][0], wid, lane);                       \
              stage_half((Bptr) + (tt + 1) * 64 + 32, (ldB),                 \
                         &sBls[s2_][1][0], wid, lane);                       \
            } },                                                             \
          { if (pf_) asm volatile("s_waitcnt vmcnt(8)" ::: "memory");        \
            else     asm volatile("s_waitcnt vmcnt(0)" ::: "memory");        \
            __builtin_amdgcn_sched_barrier(0); })                            \
      PH2({ ph_reads_A8(A1_, wr, r_, kg_, xr_, a_);                          \
            ph_reads_B(B1_, wc, r_, kg_, xr_, b_); },                        \
          { },                                                               \
          { if (pf_) { asm volatile("s_waitcnt vmcnt(2)" ::: "memory");      \
            __builtin_amdgcn_sched_barrier(0); } })                          \
    }                                                                        \
  }

#define DECL_ACC84()                                                 \
  f32x4 acc[8][4];                                                   \
  _Pragma("unroll")                                                  \
  for (int i = 0; i < 8; ++i)                                        \
    _Pragma("unroll")                                                \
    for (int j = 0; j < 4; ++j)                                      \
      _Pragma("unroll")                                              \
      for (int q = 0; q < 4; ++q) acc[i][j][q] = 0.0f

// ---- 1) One-shot bf16 conversion of X and Wq/Wk/Wv.
__global__ __launch_bounds__(256) void prep_kernel(
    const float* __restrict__ X,
    const float* __restrict__ Wq, const float* __restrict__ Wk, const float* __restrict__ Wv,
    u16* __restrict__ Xb, u16* __restrict__ Wb)
{
  const size_t i = ((size_t)blockIdx.x * 256 + threadIdx.x) * 4;
  const size_t nx = (size_t)NROW * EMB;
  f32x4 v;
  u16* dst;
  if (i < nx) {
    v = *(const f32x4*)(X + i);
    dst = Xb + i;
  } else {
    const size_t j = i - nx;
    const int m = (int)(j / ((size_t)EMB * EMB));
    const size_t o = j - (size_t)m * EMB * EMB;
    const float* W = (m == 0) ? Wq : (m == 1) ? Wk : Wv;
    v = *(const f32x4*)(W + o);
    dst = Wb + j;
  }
  u16x4 h;
#pragma unroll
  for (int j = 0; j < 4; ++j) h[j] = f2bf(v[j]);
  *(u16x4*)dst = h;
}

// ---- 2) Fused QKV projection — R5's exact 128^2/BK32/3-buf structure (137.5 µs)
__global__ __launch_bounds__(256) void proj_kernel(
    const u16* __restrict__ Xb, const u16* __restrict__ Wb,
    const float* __restrict__ bq, const float* __restrict__ bk, const float* __restrict__ bv,
    u16* __restrict__ Qb, u16* __restrict__ Kb, u16* __restrict__ VT)
{
  __shared__ alignas(16) u16 sA0[128 * 32], sA1[128 * 32], sA2[128 * 32];
  __shared__ alignas(16) u16 sB0[128 * 32], sB1[128 * 32], sB2[128 * 32];

  const int nwg = (EMB / 128) * (NROW / 128) * 3;       // 3072
  int wg = xcd_swz(blockIdx.x, nwg);
  const int n0 = (wg & 7) * 128;        wg >>= 3;
  const int m0 = (wg & 127) * 128;      wg >>= 7;
  const int mat = wg;

  const int t = threadIdx.x, lane = t & 63, wid = t >> 6;
  const int wr = wid >> 1, wc = wid & 1;

  const u16* A = Xb + (size_t)m0 * EMB;
  const u16* B = Wb + (size_t)mat * EMB * EMB + (size_t)n0 * EMB;

  f32x4 acc[4][4];
#pragma unroll
  for (int i = 0; i < 4; ++i)
#pragma unroll
    for (int j = 0; j < 4; ++j)
#pragma unroll
      for (int q = 0; q < 4; ++q) acc[i][j][q] = 0.0f;

  GEMM_PIPE3_128(A, EMB, B, EMB, EMB / 32);

  const float* bias = (mat == 0) ? bq : (mat == 1) ? bk : bv;
  const int r = lane & 15, kg = lane >> 4;
#pragma unroll
  for (int i = 0; i < 4; ++i) {
#pragma unroll
    for (int j = 0; j < 4; ++j) {
      const int c = n0 + wc * 64 + j * 16 + r;
      const float bb = bias[c];
      if (mat == 2) {
        const int bi = m0 >> 11;
        const int sbase = (m0 & (SEQ - 1)) + wr * 64 + i * 16 + kg * 4;
        u16x4 hv;
#pragma unroll
        for (int rg = 0; rg < 4; ++rg) hv[rg] = f2bf(acc[i][j][rg] + bb);
        *(u16x4*)&VT[((size_t)bi * EMB + c) * SEQ + sbase] = hv;   // V^T, rg-packed
      } else {
        u16* D = (mat == 0) ? Qb : Kb;
#pragma unroll
        for (int rg = 0; rg < 4; ++rg) {
          const int row = m0 + wr * 64 + i * 16 + kg * 4 + rg;
          D[(size_t)row * EMB + c] = f2bf(acc[i][j][rg] + bb);
        }
      }
    }
  }
}

// ---- 3) scores: e = bf16(exp(gq*gk*QK/32)) -> raw (unnormalized weights).
// 256^2 2-phase (R9). No max subtraction: |s| <= ~2 — overflow-safe.
__global__ __launch_bounds__(512, 2) void scores_kernel(
    const u16* __restrict__ Qb, const u16* __restrict__ Kb,
    const float* __restrict__ gates, u16* __restrict__ raw)
{
  DECL_LDS_2PH();
  const int nwg = 8 * 8 * NBAT;                         // 512
  int wg = xcd_swz(blockIdx.x, nwg);
  const int n0 = (wg & 7) * 256;        wg >>= 3;
  const int q0 = (wg & 7) * 256;        wg >>= 3;
  const int b  = wg;

  const int t = threadIdx.x, lane = t & 63, wid = t >> 6;
  const int wr = wid >> 2, wc = wid & 3;

  const u16* A = Qb + ((size_t)b * SEQ + q0) * EMB;
  const u16* B = Kb + ((size_t)b * SEQ + n0) * EMB;

  DECL_ACC84();
  GEMM_2PH(A, EMB, B, EMB, EMB / 64);

  const float* gb = gates + (size_t)b * SEQ;
  u16* rawB = raw + ((size_t)b * SEQ + q0) * SEQ;
  const int r = lane & 15, kg = lane >> 4;

  float gkj[4];
#pragma unroll
  for (int j = 0; j < 4; ++j) gkj[j] = gb[n0 + wc * 64 + j * 16 + r] * 0.03125f;

#pragma unroll
  for (int i = 0; i < 8; ++i) {
#pragma unroll
    for (int rg = 0; rg < 4; ++rg) {
      const int qr = wr * 128 + i * 16 + kg * 4 + rg;
      const float gq = gb[q0 + qr];
#pragma unroll
      for (int j = 0; j < 4; ++j) {
        const int col = n0 + wc * 64 + j * 16 + r;
        rawB[(size_t)qr * SEQ + col] = f2bf(__expf(acc[i][j][rg] * gq * gkj[j]));
      }
    }
  }
}

// ---- 4) rownorm: L = sum(e) per row; attn = e/L (f32 output); invl for pv
__global__ __launch_bounds__(256) void rownorm_kernel(
    const u16* __restrict__ raw, float* __restrict__ attn, float* __restrict__ invl)
{
  const int row = blockIdx.x;
  const int t = threadIdx.x, lane = t & 63, wid = t >> 6;
  const u16* rp = raw + (size_t)row * SEQ + t * 8;
  u16x8 h = *(const u16x8*)rp;
  float e[8];
  float s = 0.f;
#pragma unroll
  for (int j = 0; j < 8; ++j) { e[j] = bf2f(h[j]); s += e[j]; }
#pragma unroll
  for (int off = 32; off >= 1; off >>= 1) s += __shfl_xor(s, off);
  __shared__ float red[4];
  if (lane == 0) red[wid] = s;
  __syncthreads();
  s = (red[0] + red[1]) + (red[2] + red[3]);
  const float iv = 1.0f / s;
  float* ap = attn + (size_t)row * SEQ + t * 8;
  f32x4 w0, w1;
#pragma unroll
  for (int j = 0; j < 4; ++j) { w0[j] = e[j] * iv; w1[j] = e[j + 4] * iv; }
  *(f32x4*)ap       = w0;
  *(f32x4*)(ap + 4) = w1;
  if (t == 0) invl[row] = iv;
}

// ---- 5) pv: out = (E * V) * invL, 256^2 2-phase (R9)
__global__ __launch_bounds__(512, 2) void pv_kernel(
    const u16* __restrict__ Eb, const u16* __restrict__ VT,
    const float* __restrict__ invl, float* __restrict__ out)
{
  DECL_LDS_2PH();
  const int nwg = 4 * 8 * NBAT;                         // 256
  int wg = xcd_swz(blockIdx.x, nwg);
  const int d0 = (wg & 3) * 256;        wg >>= 2;
  const int q0 = (wg & 7) * 256;        wg >>= 3;
  const int b  = wg;

  const int t = threadIdx.x, lane = t & 63, wid = t >> 6;
  const int wr = wid >> 2, wc = wid & 3;

  const u16* A = Eb + ((size_t)b * SEQ + q0) * SEQ;     // unnormalized weights bf16
  const u16* B = VT + ((size_t)b * EMB + d0) * SEQ;     // V^T [d][k]

  DECL_ACC84();
  GEMM_2PH(A, SEQ, B, SEQ, SEQ / 64);

  const int r = lane & 15, kg = lane >> 4;
#pragma unroll
  for (int i = 0; i < 8; ++i) {
#pragma unroll
    for (int rg = 0; rg < 4; ++rg) {
      const int rowl = q0 + wr * 128 + i * 16 + kg * 4 + rg;
      const float iv = invl[(size_t)b * SEQ + rowl];
#pragma unroll
      for (int j = 0; j < 4; ++j) {
        const int col = d0 + wc * 64 + j * 16 + r;
        out[((size_t)b * SEQ + rowl) * EMB + col] = acc[i][j][rg] * iv;
      }
    }
  }
}

extern "C" void kernel_launch(void* const* d_in, const int* in_sizes, int n_in,
                              void* d_out, int out_size, void* d_ws, size_t ws_size,
                              hipStream_t stream) {
  const float* X  = (const float*)d_in[0];
  const float* g  = (const float*)d_in[1];
  const float* Wq = (const float*)d_in[2];
  const float* bq = (const float*)d_in[3];
  const float* Wk = (const float*)d_in[4];
  const float* bk = (const float*)d_in[5];
  const float* Wv = (const float*)d_in[6];
  const float* bv = (const float*)d_in[7];

  float* out0 = (float*)d_out;
  float* attn = out0 + (size_t)NROW * EMB;

  // ws: [region0 67MB: raw bf16 e-values; overlaid by Xb(33.5)+Wb(6.3) during
  //  prep/proj (dead before scores writes)] [VT 33.5MB] [invl 64KB] = ~101 MB
  const size_t rawN = (size_t)NBAT * SEQ * SEQ;          // 33,554,432 u16
  const size_t need = rawN * 2 + (size_t)NBAT * EMB * SEQ * 2 + (size_t)NROW * 4;
  if (ws_size < need) return;
  u16* region0 = (u16*)d_ws;
  u16* Xb  = region0;
  u16* Wb  = region0 + (size_t)NROW * EMB;
  u16* raw = region0;
  u16* VT  = region0 + rawN;
  float* invl = (float*)(VT + (size_t)NBAT * EMB * SEQ);
  // Qb/Kb live in out0 (dead until pv overwrites it)
  u16* Qb = (u16*)out0;
  u16* Kb = Qb + (size_t)NROW * EMB;

  const int prep_blocks = (int)(((size_t)NROW * EMB + (size_t)3 * EMB * EMB) / 1024);
  prep_kernel   <<<dim3(prep_blocks), 256, 0, stream>>>(X, Wq, Wk, Wv, Xb, Wb);
  proj_kernel   <<<dim3(3072), 256, 0, stream>>>(Xb, Wb, bq, bk, bv, Qb, Kb, VT);
  scores_kernel <<<dim3(512), 512, 0, stream>>>(Qb, Kb, g, raw);
  rownorm_kernel<<<dim3(NROW), 256, 0, stream>>>(raw, attn, invl);
  pv_kernel     <<<dim3(256), 512, 0, stream>>>(raw, VT, invl, out0);
}

// Round 13
// 353.421 us; speedup vs baseline: 1.0712x; 1.0023x over previous
//
#include <hip/hip_runtime.h>

#define SEQ  2048
#define EMB  1024
#define NBAT 8
#define NROW (NBAT*SEQ)   // 16384

using u16 = unsigned short;
typedef float  f32x4  __attribute__((ext_vector_type(4)));
typedef __bf16 bf16x8 __attribute__((ext_vector_type(8)));
typedef u16    u16x8  __attribute__((ext_vector_type(8)));
typedef u16    u16x4  __attribute__((ext_vector_type(4)));

__device__ __forceinline__ u16 f2bf(float x) {
  unsigned u = __builtin_bit_cast(unsigned, x);
  return (u16)((u + 0x7fffu + ((u >> 16) & 1u)) >> 16);  // RNE, finite inputs
}
__device__ __forceinline__ float bf2f(u16 h) {
  return __builtin_bit_cast(float, ((unsigned)h) << 16);
}

__device__ __forceinline__ f32x4 mfma16(u16x8 a, u16x8 b, f32x4 c) {
  return __builtin_amdgcn_mfma_f32_16x16x32_bf16(
      __builtin_bit_cast(bf16x8, a), __builtin_bit_cast(bf16x8, b), c, 0, 0, 0);
}

__device__ __forceinline__ void async_cp16(const u16* g, u16* l) {
  __builtin_amdgcn_global_load_lds(
      (const __attribute__((address_space(1))) void*)(g),
      (__attribute__((address_space(3))) void*)(l), 16, 0, 0);
}

__device__ __forceinline__ int xcd_swz(int bid, int nwg) {
  return (bid & 7) * (nwg >> 3) + (bid >> 3);
}

// ======================= 128^2 family (proj — R5-proven, untouched) ===========
__device__ __forceinline__ void gload_tile128(const u16* __restrict__ g, int ld,
                                              u16* __restrict__ lds, int wid, int lane)
{
#pragma unroll
  for (int l = 0; l < 2; ++l) {
    const int r0 = wid * 32 + l * 16;
    const u16* src = g + (size_t)(r0 + (lane >> 2)) * ld + (lane & 3) * 8;
    async_cp16(src, lds + r0 * 32);
  }
}

__device__ __forceinline__ void kstep128(const u16* __restrict__ sA,
                                         const u16* __restrict__ sB,
                                         int wr, int wc, int lane, f32x4 acc[4][4])
{
  const int r = lane & 15, kg = lane >> 4;
  u16x8 a[4], b[4];
#pragma unroll
  for (int i = 0; i < 4; ++i) {
    a[i] = *(const u16x8*)&sA[(wr * 64 + i * 16 + r) * 32 + kg * 8];
    b[i] = *(const u16x8*)&sB[(wc * 64 + i * 16 + r) * 32 + kg * 8];
  }
#pragma unroll
  for (int i = 0; i < 4; ++i)
#pragma unroll
    for (int j = 0; j < 4; ++j)
      acc[i][j] = mfma16(a[i], b[j], acc[i][j]);
}

#define GEMM_PIPE3_128(Aptr, ldA, Bptr, ldB, NTv)                    \
  gload_tile128((Aptr), (ldA), sA0, wid, lane);                      \
  gload_tile128((Bptr), (ldB), sB0, wid, lane);                      \
  gload_tile128((Aptr) + 32, (ldA), sA1, wid, lane);                 \
  gload_tile128((Bptr) + 32, (ldB), sB1, wid, lane);                 \
  {                                                                  \
    u16 *pa0 = sA0, *pa1 = sA1, *pa2 = sA2;                          \
    u16 *pb0 = sB0, *pb1 = sB1, *pb2 = sB2;                          \
    for (int tt = 0; tt < (NTv) - 1; ++tt) {                         \
      asm volatile("s_waitcnt vmcnt(4)" ::: "memory");               \
      __builtin_amdgcn_s_barrier();                                  \
      __builtin_amdgcn_sched_barrier(0);                             \
      if (tt + 2 < (NTv)) {                                          \
        gload_tile128((Aptr) + (tt + 2) * 32, (ldA), pa2, wid, lane);\
        gload_tile128((Bptr) + (tt + 2) * 32, (ldB), pb2, wid, lane);\
      }                                                              \
      kstep128(pa0, pb0, wr, wc, lane, acc);                         \
      u16* tmp = pa0; pa0 = pa1; pa1 = pa2; pa2 = tmp;               \
      tmp = pb0; pb0 = pb1; pb1 = pb2; pb2 = tmp;                    \
    }                                                                \
    asm volatile("s_waitcnt vmcnt(0)" ::: "memory");                 \
    __builtin_amdgcn_s_barrier();                                    \
    __builtin_amdgcn_sched_barrier(0);                               \
    kstep128(pa0, pb0, wr, wc, lane, acc);                           \
  }

// ======================= 256^2 2-phase family (scores/pv) =====================
__device__ __forceinline__ void stage_half(const u16* __restrict__ g, int ld,
                                           u16* __restrict__ lds, int wid, int lane)
{
  const int lr = lane >> 2;
  const int bb = (lr & 1) ^ ((lr >> 2) & 1);
  const int row16 = (lr & ~1) | bb;
  const int ck = (lane & 3) ^ ((lr & 2) | bb);
#pragma unroll
  for (int l = 0; l < 2; ++l) {
    const int r0 = wid * 32 + l * 16;
    async_cp16(g + (size_t)(r0 + row16) * ld + ck * 8, lds + r0 * 32);
  }
}

__device__ __forceinline__ void ph_reads_A8(const u16* __restrict__ sAh,
                                            int wr, int r, int kg, int xr, u16x8 a[8])
{
#pragma unroll
  for (int i = 0; i < 8; ++i) {
    const int row = wr * 128 + i * 16 + r;
    a[i] = *(const u16x8*)&sAh[(row * 32 + kg * 8) ^ xr];
  }
}
__device__ __forceinline__ void ph_reads_B(const u16* __restrict__ sBh,
                                           int wc, int r, int kg, int xr, u16x8 b[4])
{
#pragma unroll
  for (int j = 0; j < 4; ++j) {
    const int row = wc * 64 + j * 16 + r;
    b[j] = *(const u16x8*)&sBh[(row * 32 + kg * 8) ^ xr];
  }
}

__device__ __forceinline__ void mfma_block8(const u16x8 a[8], const u16x8 b[4],
                                            f32x4 (*accp)[4])
{
#pragma unroll
  for (int i = 0; i < 8; ++i)
#pragma unroll
    for (int j = 0; j < 4; ++j)
      accp[i][j] = mfma16(a[i], b[j], accp[i][j]);
}

#define DECL_LDS_2PH()                                                       \
  __shared__ alignas(16) u16 sAls[2][2][256 * 32];                           \
  __shared__ alignas(16) u16 sBls[2][2][256 * 32]

// Stage order [A0,B0,A1,B1]. Wait accounting (incl. pv's 2 WB stores, which
// queue AFTER the batch): P0 vmcnt(8) forces batch-t tail + prior stores;
// P1 vmcnt(4) forces A0,B0(,A1) of t+1. No hard lgkm drain: compiler emits
// fine-grained waits via data-deps. Trailing __VA_ARGS__ = per-tile
// write-back code (pv only) — NO #pragma allowed inside (macro arg).
#define GEMM_2PH(Aptr, ldA, Bptr, ldB, NTv, ...)                             \
  {                                                                          \
    const int r_ = lane & 15, kg_ = lane >> 4;                               \
    const int xr_ = (r_ & 7) << 3;                                           \
    stage_half((Aptr),      (ldA), &sAls[0][0][0], wid, lane);               \
    stage_half((Bptr),      (ldB), &sBls[0][0][0], wid, lane);               \
    stage_half((Aptr) + 32, (ldA), &sAls[0][1][0], wid, lane);               \
    stage_half((Bptr) + 32, (ldB), &sBls[0][1][0], wid, lane);               \
    asm volatile("s_waitcnt vmcnt(4)" ::: "memory");                         \
    __builtin_amdgcn_sched_barrier(0);                                       \
    __builtin_amdgcn_s_barrier();                                            \
    u16x8 a_[8], b_[4];                                                      \
    for (int tt = 0; tt < (NTv); ++tt) {                                     \
      const int s_ = tt & 1, s2_ = s_ ^ 1;                                   \
      const u16* A0_ = &sAls[s_][0][0]; const u16* A1_ = &sAls[s_][1][0];    \
      const u16* B0_ = &sBls[s_][0][0]; const u16* B1_ = &sBls[s_][1][0];    \
      const bool pf_ = (tt + 1 < (NTv));                                     \
      /* ---- P0 ---- */                                                     \
      ph_reads_A8(A0_, wr, r_, kg_, xr_, a_);                                \
      ph_reads_B(B0_, wc, r_, kg_, xr_, b_);                                 \
      if (pf_) {                                                             \
        stage_half((Aptr) + (tt + 1) * 64,      (ldA), &sAls[s2_][0][0], wid, lane); \
        stage_half((Bptr) + (tt + 1) * 64,      (ldB), &sBls[s2_][0][0], wid, lane); \
        stage_half((Aptr) + (tt + 1) * 64 + 32, (ldA), &sAls[s2_][1][0], wid, lane); \
        stage_half((Bptr) + (tt + 1) * 64 + 32, (ldB), &sBls[s2_][1][0], wid, lane); \
        asm volatile("s_waitcnt vmcnt(8)" ::: "memory");                     \
      } else {                                                               \
        asm volatile("s_waitcnt vmcnt(0)" ::: "memory");                     \
      }                                                                      \
      __builtin_amdgcn_sched_barrier(0);                                     \
      __builtin_amdgcn_s_barrier();                                          \
      __builtin_amdgcn_s_setprio(1);                                         \
      mfma_block8(a_, b_, acc);                                              \
      __builtin_amdgcn_s_setprio(0);                                         \
      __builtin_amdgcn_s_barrier();                                          \
      /* ---- P1 ---- */                                                     \
      ph_reads_A8(A1_, wr, r_, kg_, xr_, a_);                                \
      ph_reads_B(B1_, wc, r_, kg_, xr_, b_);                                 \
      __VA_ARGS__                                                            \
      if (pf_) { asm volatile("s_waitcnt vmcnt(4)" ::: "memory");            \
                 __builtin_amdgcn_sched_barrier(0); }                        \
      __builtin_amdgcn_s_barrier();                                          \
      __builtin_amdgcn_s_setprio(1);                                         \
      mfma_block8(a_, b_, acc);                                              \
      __builtin_amdgcn_s_setprio(0);                                         \
      __builtin_amdgcn_s_barrier();                                          \
    }                                                                        \
  }

#define DECL_ACC84()                                                 \
  f32x4 acc[8][4];                                                   \
  _Pragma("unroll")                                                  \
  for (int i = 0; i < 8; ++i)                                        \
    _Pragma("unroll")                                                \
    for (int j = 0; j < 4; ++j)                                      \
      _Pragma("unroll")                                              \
      for (int q = 0; q < 4; ++q) acc[i][j][q] = 0.0f

// ---- 1) One-shot bf16 conversion of X and Wq/Wk/Wv.
__global__ __launch_bounds__(256) void prep_kernel(
    const float* __restrict__ X,
    const float* __restrict__ Wq, const float* __restrict__ Wk, const float* __restrict__ Wv,
    u16* __restrict__ Xb, u16* __restrict__ Wb)
{
  const size_t i = ((size_t)blockIdx.x * 256 + threadIdx.x) * 4;
  const size_t nx = (size_t)NROW * EMB;
  f32x4 v;
  u16* dst;
  if (i < nx) {
    v = *(const f32x4*)(X + i);
    dst = Xb + i;
  } else {
    const size_t j = i - nx;
    const int m = (int)(j / ((size_t)EMB * EMB));
    const size_t o = j - (size_t)m * EMB * EMB;
    const float* W = (m == 0) ? Wq : (m == 1) ? Wk : Wv;
    v = *(const f32x4*)(W + o);
    dst = Wb + j;
  }
  u16x4 h;
#pragma unroll
  for (int j = 0; j < 4; ++j) h[j] = f2bf(v[j]);
  *(u16x4*)dst = h;
}

// ---- 2) Fused QKV projection — R5-exact (137.5 µs measured)
__global__ __launch_bounds__(256) void proj_kernel(
    const u16* __restrict__ Xb, const u16* __restrict__ Wb,
    const float* __restrict__ bq, const float* __restrict__ bk, const float* __restrict__ bv,
    u16* __restrict__ Qb, u16* __restrict__ Kb, u16* __restrict__ VT)
{
  __shared__ alignas(16) u16 sA0[128 * 32], sA1[128 * 32], sA2[128 * 32];
  __shared__ alignas(16) u16 sB0[128 * 32], sB1[128 * 32], sB2[128 * 32];

  const int nwg = (EMB / 128) * (NROW / 128) * 3;       // 3072
  int wg = xcd_swz(blockIdx.x, nwg);
  const int n0 = (wg & 7) * 128;        wg >>= 3;
  const int m0 = (wg & 127) * 128;      wg >>= 7;
  const int mat = wg;

  const int t = threadIdx.x, lane = t & 63, wid = t >> 6;
  const int wr = wid >> 1, wc = wid & 1;

  const u16* A = Xb + (size_t)m0 * EMB;
  const u16* B = Wb + (size_t)mat * EMB * EMB + (size_t)n0 * EMB;

  f32x4 acc[4][4];
#pragma unroll
  for (int i = 0; i < 4; ++i)
#pragma unroll
    for (int j = 0; j < 4; ++j)
#pragma unroll
      for (int q = 0; q < 4; ++q) acc[i][j][q] = 0.0f;

  GEMM_PIPE3_128(A, EMB, B, EMB, EMB / 32);

  const float* bias = (mat == 0) ? bq : (mat == 1) ? bk : bv;
  const int r = lane & 15, kg = lane >> 4;
#pragma unroll
  for (int i = 0; i < 4; ++i) {
#pragma unroll
    for (int j = 0; j < 4; ++j) {
      const int c = n0 + wc * 64 + j * 16 + r;
      const float bb = bias[c];
      if (mat == 2) {
        const int bi = m0 >> 11;
        const int sbase = (m0 & (SEQ - 1)) + wr * 64 + i * 16 + kg * 4;
        u16x4 hv;
#pragma unroll
        for (int rg = 0; rg < 4; ++rg) hv[rg] = f2bf(acc[i][j][rg] + bb);
        *(u16x4*)&VT[((size_t)bi * EMB + c) * SEQ + sbase] = hv;   // V^T, rg-packed
      } else {
        u16* D = (mat == 0) ? Qb : Kb;
#pragma unroll
        for (int rg = 0; rg < 4; ++rg) {
          const int row = m0 + wr * 64 + i * 16 + kg * 4 + rg;
          D[(size_t)row * EMB + c] = f2bf(acc[i][j][rg] + bb);
        }
      }
    }
  }
}

// ---- 3) scores: e = bf16(exp(gq*gk*QK/32)) -> raw; per-(row,64col) partial
// sums of e -> part. No max subtraction: |s| <= ~2 — overflow-safe.
__global__ __launch_bounds__(512, 2) void scores_kernel(
    const u16* __restrict__ Qb, const u16* __restrict__ Kb,
    const float* __restrict__ gates, u16* __restrict__ raw,
    float* __restrict__ part)
{
  DECL_LDS_2PH();
  const int nwg = 8 * 8 * NBAT;                         // 512
  int wg = xcd_swz(blockIdx.x, nwg);
  const int n0 = (wg & 7) * 256;        wg >>= 3;
  const int q0 = (wg & 7) * 256;        wg >>= 3;
  const int b  = wg;

  const int t = threadIdx.x, lane = t & 63, wid = t >> 6;
  const int wr = wid >> 2, wc = wid & 3;

  const u16* A = Qb + ((size_t)b * SEQ + q0) * EMB;
  const u16* B = Kb + ((size_t)b * SEQ + n0) * EMB;

  DECL_ACC84();
  GEMM_2PH(A, EMB, B, EMB, EMB / 64, {});

  const float* gb = gates + (size_t)b * SEQ;
  u16* rawB = raw + ((size_t)b * SEQ + q0) * SEQ;
  const int r = lane & 15, kg = lane >> 4;
  const int tix = (n0 >> 6) + wc;                       // 0..31

  float gkj[4];
#pragma unroll
  for (int j = 0; j < 4; ++j) gkj[j] = gb[n0 + wc * 64 + j * 16 + r] * 0.03125f;

#pragma unroll
  for (int i = 0; i < 8; ++i) {
#pragma unroll
    for (int rg = 0; rg < 4; ++rg) {
      const int qr = wr * 128 + i * 16 + kg * 4 + rg;
      const float gq = gb[q0 + qr];
      float psum = 0.f;
#pragma unroll
      for (int j = 0; j < 4; ++j) {
        const int col = n0 + wc * 64 + j * 16 + r;
        const u16 h = f2bf(__expf(acc[i][j][rg] * gq * gkj[j]));
        rawB[(size_t)qr * SEQ + col] = h;
        psum += bf2f(h);
      }
#pragma unroll
      for (int m = 1; m < 16; m <<= 1) psum += __shfl_xor(psum, m);
      if (r == 0) part[((size_t)b * SEQ + q0 + qr) * 32 + tix] = psum;
    }
  }
}

// ---- 4) reduce: invl[row] = 1 / sum of 32 partials
__global__ __launch_bounds__(256) void reduce_kernel(
    const float* __restrict__ part, float* __restrict__ invl)
{
  const int row = blockIdx.x * 256 + threadIdx.x;
  const float* p = part + (size_t)row * 32;
  float s = 0.f;
#pragma unroll
  for (int i = 0; i < 8; ++i) {
    f32x4 v = *(const f32x4*)(p + i * 4);
    s += (v[0] + v[1]) + (v[2] + v[3]);
  }
  invl[row] = 1.0f / s;
}

// ---- 5) pv: out = (E*V)*invL; ALSO writes attn = e*invL from the staged LDS
// e-tiles (replaces rownorm). Block dd writes cols [kt*64+dd*16, +16) per tile.
__global__ __launch_bounds__(512, 2) void pv_kernel(
    const u16* __restrict__ Eb, const u16* __restrict__ VT,
    const float* __restrict__ invl, float* __restrict__ attn,
    float* __restrict__ out)
{
  DECL_LDS_2PH();
  const int nwg = 4 * 8 * NBAT;                         // 256
  int wg = xcd_swz(blockIdx.x, nwg);
  const int dd = wg & 3;                wg >>= 2;       // d-tile index 0..3
  const int d0 = dd * 256;
  const int q0 = (wg & 7) * 256;        wg >>= 3;
  const int b  = wg;

  const int t = threadIdx.x, lane = t & 63, wid = t >> 6;
  const int wr = wid >> 2, wc = wid & 3;

  const u16* A = Eb + ((size_t)b * SEQ + q0) * SEQ;     // unnormalized e bf16
  const u16* B = VT + ((size_t)b * EMB + d0) * SEQ;     // V^T [d][k]

  // write-back assignments: thread covers row prow (=t>>1), 16B chunk pc2
  const int prow = t >> 1, pc2 = t & 1;
  const float invl_r = invl[(size_t)b * SEQ + q0 + prow];
  float* attnB = attn + ((size_t)b * SEQ + q0) * SEQ;

  DECL_ACC84();
  GEMM_2PH(A, SEQ, B, SEQ, SEQ / 64,
    {
      const u16* hb_ = (dd >= 2) ? A1_ : A0_;
      const int ch_ = (dd & 1) * 2 + pc2;
      u16x8 hv_ = *(const u16x8*)&hb_[(prow * 32 + ch_ * 8) ^ ((prow & 7) << 3)];
      f32x4 w0_, w1_;
      w0_[0] = bf2f(hv_[0]) * invl_r;  w0_[1] = bf2f(hv_[1]) * invl_r;
      w0_[2] = bf2f(hv_[2]) * invl_r;  w0_[3] = bf2f(hv_[3]) * invl_r;
      w1_[0] = bf2f(hv_[4]) * invl_r;  w1_[1] = bf2f(hv_[5]) * invl_r;
      w1_[2] = bf2f(hv_[6]) * invl_r;  w1_[3] = bf2f(hv_[7]) * invl_r;
      float* ap_ = attnB + (size_t)prow * SEQ + tt * 64 + dd * 16 + pc2 * 8;
      *(f32x4*)ap_ = w0_;
      *(f32x4*)(ap_ + 4) = w1_;
    });

  const int r = lane & 15, kg = lane >> 4;
#pragma unroll
  for (int i = 0; i < 8; ++i) {
#pragma unroll
    for (int rg = 0; rg < 4; ++rg) {
      const int rowl = q0 + wr * 128 + i * 16 + kg * 4 + rg;
      const float iv = invl[(size_t)b * SEQ + rowl];
#pragma unroll
      for (int j = 0; j < 4; ++j) {
        const int col = d0 + wc * 64 + j * 16 + r;
        out[((size_t)b * SEQ + rowl) * EMB + col] = acc[i][j][rg] * iv;
      }
    }
  }
}

extern "C" void kernel_launch(void* const* d_in, const int* in_sizes, int n_in,
                              void* d_out, int out_size, void* d_ws, size_t ws_size,
                              hipStream_t stream) {
  const float* X  = (const float*)d_in[0];
  const float* g  = (const float*)d_in[1];
  const float* Wq = (const float*)d_in[2];
  const float* bq = (const float*)d_in[3];
  const float* Wk = (const float*)d_in[4];
  const float* bk = (const float*)d_in[5];
  const float* Wv = (const float*)d_in[6];
  const float* bv = (const float*)d_in[7];

  float* out0 = (float*)d_out;
  float* attn = out0 + (size_t)NROW * EMB;

  // ws: [region0 67MB: raw bf16 e; overlaid by Xb+Wb during prep/proj]
  //     [VT 33.5MB] [part 2MB] [invl 64KB]  = ~103 MB
  const size_t rawN = (size_t)NBAT * SEQ * SEQ;          // 33,554,432 u16
  const size_t need = rawN * 2 + (size_t)NBAT * EMB * SEQ * 2
                    + (size_t)NROW * 32 * 4 + (size_t)NROW * 4;
  if (ws_size < need) return;
  u16* region0 = (u16*)d_ws;
  u16* Xb  = region0;
  u16* Wb  = region0 + (size_t)NROW * EMB;
  u16* raw = region0;
  u16* VT  = region0 + rawN;
  float* part = (float*)(VT + (size_t)NBAT * EMB * SEQ);
  float* invl = part + (size_t)NROW * 32;
  // Qb/Kb live in out0 (dead until pv overwrites it)
  u16* Qb = (u16*)out0;
  u16* Kb = Qb + (size_t)NROW * EMB;

  const int prep_blocks = (int)(((size_t)NROW * EMB + (size_t)3 * EMB * EMB) / 1024);
  prep_kernel   <<<dim3(prep_blocks), 256, 0, stream>>>(X, Wq, Wk, Wv, Xb, Wb);
  proj_kernel   <<<dim3(3072), 256, 0, stream>>>(Xb, Wb, bq, bk, bv, Qb, Kb, VT);
  scores_kernel <<<dim3(512), 512, 0, stream>>>(Qb, Kb, g, raw, part);
  reduce_kernel <<<dim3(NROW / 256), 256, 0, stream>>>(part, invl);
  pv_kernel     <<<dim3(256), 512, 0, stream>>>(raw, VT, invl, attn, out0);
}